// Round 4
// baseline (194.305 us; speedup 1.0000x reference)
//
#include <hip/hip_runtime.h>
#include <stdint.h>

// ===========================================================================
// AnchorDataGenerator (Faster R-CNN anchor target layer), MI355X / gfx950
// Round 4: 2 launches.
//  - k_pre: zeroes ws control region (hist/counters/flag/sel) + windowed
//    per-gt max IoU (512 blocks, 8 slices/gt).
//  - k_fat: persistent 576-block kernel doing main pass (4 anchors/thread,
//    labels+adj+mantissa in REGISTERS), LDS->global hist flush, last-block
//    subsample-boundary select, device-scope flag broadcast, emit (labels/
//    wts/candidates) straight from registers, arrive counter, then blocks
//    0/1 resolve the boundary bin exactly (O(C^2) rank in LDS).
//    __launch_bounds__(256,3): >=3 blocks/CU co-resident (768 >= 576), so
//    the flag/arrive spins cannot deadlock. Counters zeroed by k_pre.
// All IoU math bit-exact vs reference (contract off, IEEE div, same order).
// ===========================================================================

#define NUM_A 9
#define HW 65536
#define N_ANCH 589824
#define NG 64
#define CAPK 128u
#define NBIN 2048
#define BIN_SHIFT 12
#define CAND_CAP 2048
#define NBLK 576

#define LAB_BG 0u
#define LAB_FG 1u
#define LAB_IGN 2u

// workspace layout (u32 units); ~12.8k u32 used (~51 KB)
#define OFF_GMAX8 0                        // 64 gts x 8 slices
#define OFF_HF    512
#define OFF_HB    (OFF_HF + NBIN)          // 2560
#define OFF_CNTF  (OFF_HF + 2*NBIN)        // 4608
#define OFF_CNTB  (OFF_CNTF + 1)           // 4609
#define OFF_ARR1  (OFF_CNTF + 2)           // 4610
#define OFF_ARR2  (OFF_CNTF + 3)           // 4611
#define OFF_FLAG  (OFF_CNTF + 4)           // 4612
#define OFF_SEL   (OFF_CNTF + 8)           // 4616..4623: {bin,below,need,K} x2
#define OFF_CANDF 4624                     // byte 18496, 8B aligned; u64 keys
#define OFF_CANDB (OFF_CANDF + 2*CAND_CAP) // 8720
#define ZERO_BEG  OFF_HF
#define ZERO_END  OFF_CANDF
#define NZ        (ZERO_END - ZERO_BEG)    // 4112 words

__constant__ float BA[NUM_A][4] = {
  { -84.f,  -40.f,  99.f,  55.f}, {-176.f,  -88.f, 191.f, 103.f},
  {-360.f, -184.f, 375.f, 199.f}, { -56.f,  -56.f,  71.f,  71.f},
  {-120.f, -120.f, 135.f, 135.f}, {-248.f, -248.f, 263.f, 263.f},
  { -36.f,  -80.f,  51.f,  95.f}, { -80.f, -168.f,  95.f, 183.f},
  {-168.f, -344.f, 183.f, 359.f}};

__host__ __device__ static inline void tf2x32(uint32_t k0, uint32_t k1,
                                              uint32_t x0, uint32_t x1,
                                              uint32_t* o0, uint32_t* o1) {
  const uint32_t ks2 = k0 ^ k1 ^ 0x1BD11BDAu;
#define TF_R(r) { x0 += x1; x1 = (x1 << (r)) | (x1 >> (32 - (r))); x1 ^= x0; }
  x0 += k0; x1 += k1;
  TF_R(13) TF_R(15) TF_R(26) TF_R(6)
  x0 += k1;  x1 += ks2 + 1u;
  TF_R(17) TF_R(29) TF_R(16) TF_R(24)
  x0 += ks2; x1 += k0 + 2u;
  TF_R(13) TF_R(15) TF_R(26) TF_R(6)
  x0 += k0;  x1 += k1 + 3u;
  TF_R(17) TF_R(29) TF_R(16) TF_R(24)
  x0 += k1;  x1 += ks2 + 4u;
  TF_R(13) TF_R(15) TF_R(26) TF_R(6)
  x0 += ks2; x1 += k0 + 5u;
#undef TF_R
  *o0 = x0; *o1 = x1;
}

__device__ static inline uint32_t mant_of(uint32_t k0, uint32_t k1, uint32_t n) {
  uint32_t o0, o1;
  tf2x32(k0, k1, 0u, n, &o0, &o1);   // partitionable: counter = (hi=0, lo=n)
  return (o0 ^ o1) >> 9;             // 23-bit mantissa
}

// IoU in the reference's exact fp32 op order (contraction OFF).
__device__ static inline float iou1(float a0, float a1, float a2, float a3,
                                    float aarea, float g0, float g1, float g2,
                                    float g3, float garea) {
  #pragma clang fp contract(off)
  float ix1 = fmaxf(a0, g0);
  float iy1 = fmaxf(a1, g1);
  float ix2 = fminf(a2, g2);
  float iy2 = fminf(a3, g3);
  float iw = ix2 - ix1 + 1.0f;
  float ih = iy2 - iy1 + 1.0f;
  float inter = (iw > 0.0f && ih > 0.0f) ? iw * ih : 0.0f;
  float den = aarea + garea - inter;
  return inter / den;                  // IEEE-rounded div
}

// ---- k_pre: zero ctrl region + per-gt windowed max IoU (8 slices/gt) ------
__global__ __launch_bounds__(256) void k_pre(const float* __restrict__ gt,
                                             const int* __restrict__ imw_p,
                                             const int* __restrict__ imh_p,
                                             uint32_t* __restrict__ ws) {
  #pragma clang fp contract(off)
  int tid = threadIdx.x;
  int b = blockIdx.x;
  int gid = b * 256 + tid;
  if (gid < NZ) ws[ZERO_BEG + gid] = 0u;

  int g = b >> 3, sl = b & 7;
  float g0 = gt[g*4+0], g1 = gt[g*4+1], g2 = gt[g*4+2], g3 = gt[g*4+3];
  float gw = g2 - g0 + 1.0f, gh = g3 - g1 + 1.0f;
  float ga = (gw > 0.0f && gh > 0.0f) ? gw * gh : 0.0f;
  float imw = (float)imw_p[0], imh = (float)imh_p[0];

  float mx = 0.0f;   // g_max >= 0 always (some valid anchor exists)
  for (int a = 0; a < NUM_A; a++) {
    float b0 = BA[a][0], b1 = BA[a][1], b2 = BA[a][2], b3 = BA[a][3];
    int wlo = max(0,   (int)floorf((g0 - 1.0f - b2) * 0.0625f));
    int whi = min(255, (int)ceilf ((g2 + 1.0f - b0) * 0.0625f));
    int hlo = max(0,   (int)floorf((g1 - 1.0f - b3) * 0.0625f));
    int hhi = min(255, (int)ceilf ((g3 + 1.0f - b1) * 0.0625f));
    int wx = whi - wlo + 1, wy = hhi - hlo + 1;
    if (wx <= 0 || wy <= 0) continue;
    int tot = wx * wy;
    for (int idx = sl * 256 + tid; idx < tot; idx += 2048) {
      int h = hlo + idx / wx, w = wlo + idx % wx;
      float sx = (float)(w << 4), sy = (float)(h << 4);
      float x1 = b0 + sx, y1 = b1 + sy, x2 = b2 + sx, y2 = b3 + sy;
      float aw = x2 - x1 + 1.0f, ah = y2 - y1 + 1.0f;
      float aarea = aw * ah;
      bool vld = (x1 >= 0.0f) && (y1 >= 0.0f) && (x2 < imw) && (y2 < imh);
      float o = iou1(x1, y1, x2, y2, aarea, g0, g1, g2, g3, ga);
      if (vld) mx = fmaxf(mx, o);
    }
  }
  #pragma unroll
  for (int s = 32; s >= 1; s >>= 1) mx = fmaxf(mx, __shfl_xor(mx, s, 64));
  __shared__ float wmax[4];
  if ((tid & 63) == 0) wmax[tid >> 6] = mx;
  __syncthreads();
  if (tid == 0) {
    float m = fmaxf(fmaxf(wmax[0], wmax[1]), fmaxf(wmax[2], wmax[3]));
    ws[OFF_GMAX8 + g * 8 + sl] = __float_as_uint(m);
  }
}

// ---- k_fat: main + select + emit + fixup, one persistent dispatch ---------
__global__ __launch_bounds__(256, 3) void k_fat(const float* __restrict__ gt,
                                                const int* __restrict__ imw_p,
                                                const int* __restrict__ imh_p,
                                                float* __restrict__ out_lab,
                                                float* __restrict__ out_adj,
                                                float* __restrict__ out_wts,
                                                uint32_t* __restrict__ ws,
                                                uint32_t kf0, uint32_t kf1,
                                                uint32_t kb0, uint32_t kb1) {
  #pragma clang fp contract(off)
  __shared__ float sg0[NG], sg1[NG], sg2[NG], sg3[NG], sga[NG], sgm[NG];
  __shared__ uint64_t sbuf[NBIN];          // 16 KB: hist (as u32[4096]) / cands
  __shared__ unsigned long long sMask[4];
  __shared__ int sAnyZero, sLast;
  __shared__ uint32_t ssel[8];
  uint32_t* sh = (uint32_t*)sbuf;          // 2*NBIN u32
  int tid = threadIdx.x;
  {
    uint4* sh4 = (uint4*)sh;
    #pragma unroll
    for (int k = 0; k < 4; k++) sh4[tid + k * 256] = make_uint4(0, 0, 0, 0);
  }
  if (tid == 0) sAnyZero = 0;
  if (tid < NG) {
    const float4 g4 = ((const float4*)gt)[tid];
    sg0[tid] = g4.x; sg1[tid] = g4.y; sg2[tid] = g4.z; sg3[tid] = g4.w;
    float gw = g4.z - g4.x + 1.0f, gh = g4.w - g4.y + 1.0f;
    sga[tid] = (gw > 0.0f && gh > 0.0f) ? gw * gh : 0.0f;
    uint32_t mm = 0u;
    #pragma unroll
    for (int j = 0; j < 8; j++) mm = max(mm, ws[OFF_GMAX8 + tid * 8 + j]);
    sgm[tid] = __uint_as_float(mm);
    if (mm == 0u) atomicOr(&sAnyZero, 1);
  }
  __syncthreads();

  int b = blockIdx.x;
  int a = b >> 6, hb = (b & 63) << 2;      // anchor type, 4 rows hb..hb+3
  float BA0 = BA[a][0], BA1 = BA[a][1], BA2 = BA[a][2], BA3 = BA[a][3];

  // per-wave y-mask: wave r handles row hb+r; lane = gt index
  {
    int wv = tid >> 6, g = tid & 63;
    float sy = (float)((hb + wv) << 4);
    float ihp = fminf(BA3 + sy, sg3[g]) - fmaxf(BA1 + sy, sg1[g]) + 1.0f;
    unsigned long long mk = __ballot(ihp > 0.0f);
    if (g == 0) sMask[wv] = mk;
  }
  __syncthreads();

  float imw = (float)imw_p[0], imh = (float)imh_p[0];
  int w = tid;
  float sx = (float)(w << 4);
  float A0 = BA0 + sx, A2 = BA2 + sx;
  float aw = A2 - A0 + 1.0f;
  float A1v[4], A3v[4];
  #pragma unroll
  for (int r = 0; r < 4; r++) {
    float sy = (float)((hb + r) << 4);
    A1v[r] = BA1 + sy; A3v[r] = BA3 + sy;
  }
  float ah = A3v[0] - A1v[0] + 1.0f;
  float aarea = aw * ah;                   // exact ints -> bit-exact
  bool xv = (A0 >= 0.0f) && (A2 < imw);

  unsigned long long mk0 = sMask[0], mk1 = sMask[1],
                     mk2 = sMask[2], mk3 = sMask[3];
  unsigned long long uni = mk0 | mk1 | mk2 | mk3;
  float amaxv[4] = {0.f, 0.f, 0.f, 0.f};
  int bgv[4] = {0, 0, 0, 0};
  uint32_t afv = 0u;
  while (uni) {
    int g = __ffsll(uni) - 1;
    uni &= uni - 1;
    float iw = fminf(A2, sg2[g]) - fmaxf(A0, sg0[g]) + 1.0f;
    if (!__any(iw > 0.0f)) continue;
    if (iw > 0.0f) {
      float base = aarea + sga[g];
      float gy1 = sg1[g], gy2 = sg3[g], gm = sgm[g];
#define DO_ROW(r, mk)                                                     \
      if ((mk >> g) & 1ull) {                                             \
        float ih = fminf(A3v[r], gy2) - fmaxf(A1v[r], gy1) + 1.0f;        \
        float inter = iw * ih;                                            \
        float o = inter / (base - inter);                                 \
        if (o > amaxv[r]) { amaxv[r] = o; bgv[r] = g; }                   \
        if (o == gm) afv |= (1u << r);                                    \
      }
      DO_ROW(0, mk0) DO_ROW(1, mk1) DO_ROW(2, mk2) DO_ROW(3, mk3)
#undef DO_ROW
    }
  }

  bool anyZ = (sAnyZero != 0);
  uint32_t labm[4];
  #pragma unroll
  for (int r = 0; r < 4; r++) {
    int hw = (hb + r) * 256 + w;
    bool valid = xv && (A1v[r] >= 0.0f) && (A3v[r] < imh);
    float amax = amaxv[r];
    bool anyfg = (((afv >> r) & 1u) || anyZ) && valid;
    uint32_t lab;
    if (!valid)                       lab = LAB_IGN;
    else if (anyfg || amax >= 0.7f)   lab = LAB_FG;
    else if (amax < 0.3f)             lab = LAB_BG;
    else                              lab = LAB_IGN;

    float adj0 = 0.f, adj1 = 0.f, adj2 = 0.f, adj3 = 0.f;
    if (valid) {
      int bg = bgv[r];
      float G0 = sg0[bg], G1 = sg1[bg], G2 = sg2[bg], G3 = sg3[bg];
      float ax = (A2 + A0) * 0.5f, ay = (A3v[r] + A1v[r]) * 0.5f;
      float gwm = G2 - G0 + 1.0f, ghm = G3 - G1 + 1.0f;
      float gx = (G2 + G0) * 0.5f, gy = (G3 + G1) * 0.5f;
      adj0 = (gx - ax) / aw;
      adj1 = (gy - ay) / ah;
      adj2 = logf(gwm / aw);
      adj3 = logf(ghm / ah);
    }
    int c4 = a * 4;
    out_adj[(c4 + 0) * HW + hw] = adj0;
    out_adj[(c4 + 1) * HW + hw] = adj1;
    out_adj[(c4 + 2) * HW + hw] = adj2;
    out_adj[(c4 + 3) * HW + hw] = adj3;

    uint32_t m = 0u;
    uint32_t n = (uint32_t)(hw * 9 + a);   // original anchor index (tie-break)
    if (lab != LAB_IGN) {
      uint32_t kk0 = (lab == LAB_FG) ? kf0 : kb0;
      uint32_t kk1 = (lab == LAB_FG) ? kf1 : kb1;
      m = mant_of(kk0, kk1, n);
      atomicAdd(&sh[((lab == LAB_FG) ? 0 : NBIN) + (m >> BIN_SHIFT)], 1u);
    }
    labm[r] = (lab << 24) | m;
  }

  // flush LDS hist -> global, then arrive
  __syncthreads();
  for (int i = tid; i < 2 * NBIN; i += 256) {
    uint32_t v = sh[i];
    if (v) atomicAdd(&ws[OFF_HF + i], v);
  }
  __syncthreads();
  if (tid == 0) {
    uint32_t prev = __hip_atomic_fetch_add(&ws[OFF_ARR1], 1u,
                                           __ATOMIC_ACQ_REL,
                                           __HIP_MEMORY_SCOPE_AGENT);
    sLast = (prev == NBLK - 1u) ? 1 : 0;
  }
  __syncthreads();

  if (sLast) {
    // select: boundary bin per class from the completed global histograms
    for (int cls = 0; cls < 2; cls++) {
      uint32_t* hist = ws + (cls ? OFF_HB : OFF_HF);
      uint32_t loc[8], s = 0;
      #pragma unroll
      for (int j = 0; j < 8; j++) {
        loc[j] = __hip_atomic_load(&hist[tid * 8 + j], __ATOMIC_RELAXED,
                                   __HIP_MEMORY_SCOPE_AGENT);
        s += loc[j];
      }
      sh[tid] = s; __syncthreads();
      for (int off = 1; off < 256; off <<= 1) {
        uint32_t v = (tid >= off) ? sh[tid - off] : 0u;
        __syncthreads();
        sh[tid] += v;
        __syncthreads();
      }
      uint32_t total = sh[255];
      uint32_t K = total < CAPK ? total : CAPK;
      uint32_t* sel = ws + OFF_SEL + cls * 4;
      if (tid == 0) {
        __hip_atomic_store(&sel[3], K, __ATOMIC_RELAXED,
                           __HIP_MEMORY_SCOPE_AGENT);
        if (K == 0u) {
          __hip_atomic_store(&sel[0], 0xFFFFFFFFu, __ATOMIC_RELAXED,
                             __HIP_MEMORY_SCOPE_AGENT);
        }
      }
      if (K > 0u) {
        uint32_t myC = sh[tid], pvC = (tid == 0) ? 0u : sh[tid - 1];
        if (myC >= K && pvC < K) {
          uint32_t cum = pvC; int bb = tid * 8;
          for (int j = 0; j < 8; j++) {
            if (cum + loc[j] >= K) { bb = tid * 8 + j; break; }
            cum += loc[j];
          }
          __hip_atomic_store(&sel[0], (uint32_t)bb, __ATOMIC_RELAXED,
                             __HIP_MEMORY_SCOPE_AGENT);
          __hip_atomic_store(&sel[1], cum, __ATOMIC_RELAXED,
                             __HIP_MEMORY_SCOPE_AGENT);
          __hip_atomic_store(&sel[2], K - cum, __ATOMIC_RELAXED,
                             __HIP_MEMORY_SCOPE_AGENT);
        }
      }
      __syncthreads();
    }
    if (tid == 0)
      __hip_atomic_store(&ws[OFF_FLAG], 1u, __ATOMIC_RELEASE,
                         __HIP_MEMORY_SCOPE_AGENT);
  }

  // all blocks wait for select results
  if (tid == 0) {
    while (__hip_atomic_load(&ws[OFF_FLAG], __ATOMIC_ACQUIRE,
                             __HIP_MEMORY_SCOPE_AGENT) == 0u)
      __builtin_amdgcn_s_sleep(2);
  }
  __syncthreads();
  if (tid < 8)
    ssel[tid] = __hip_atomic_load(&ws[OFF_SEL + tid], __ATOMIC_RELAXED,
                                  __HIP_MEMORY_SCOPE_AGENT);
  __syncthreads();

  // emit from registers
  uint32_t bf = ssel[0], bbs = ssel[4];
  uint32_t Kf = ssel[3], Kb = ssel[7];
  float inv = 1.0f / (float)(Kf + Kb);     // 1/num_ni
  uint64_t* candf = (uint64_t*)(ws + OFF_CANDF);
  uint64_t* candb = (uint64_t*)(ws + OFF_CANDB);
  #pragma unroll
  for (int r = 0; r < 4; r++) {
    int hw = (hb + r) * 256 + w;
    uint32_t lab = labm[r] >> 24;
    uint32_t m = labm[r] & 0x7FFFFFu;
    uint32_t n = (uint32_t)(hw * 9 + a);
    float outv = 2.0f, wv = 0.0f;
    if (lab == LAB_FG) {
      uint32_t bn = m >> BIN_SHIFT;
      if (bn < bf) { outv = 1.0f; wv = inv; }
      else if (bn == bf) {
        uint32_t idx = atomicAdd(&ws[OFF_CNTF], 1u);
        if (idx < CAND_CAP)
          __hip_atomic_store(&candf[idx], ((uint64_t)m << 20) | (uint64_t)n,
                             __ATOMIC_RELAXED, __HIP_MEMORY_SCOPE_AGENT);
      }
    } else if (lab == LAB_BG) {
      uint32_t bn = m >> BIN_SHIFT;
      if (bn < bbs) { outv = 0.0f; }
      else if (bn == bbs) {
        uint32_t idx = atomicAdd(&ws[OFF_CNTB], 1u);
        if (idx < CAND_CAP)
          __hip_atomic_store(&candb[idx], ((uint64_t)m << 20) | (uint64_t)n,
                             __ATOMIC_RELAXED, __HIP_MEMORY_SCOPE_AGENT);
      }
    }
    out_lab[a * HW + hw] = outv;
    int c4 = a * 4;
    out_wts[(c4 + 0) * HW + hw] = wv;
    out_wts[(c4 + 1) * HW + hw] = wv;
    out_wts[(c4 + 2) * HW + hw] = wv;
    out_wts[(c4 + 3) * HW + hw] = wv;
  }

  // arrive2; blocks 0/1 resolve the boundary bins exactly
  __syncthreads();
  if (tid == 0)
    __hip_atomic_fetch_add(&ws[OFF_ARR2], 1u, __ATOMIC_ACQ_REL,
                           __HIP_MEMORY_SCOPE_AGENT);
  if (b < 2) {
    if (tid == 0) {
      while (__hip_atomic_load(&ws[OFF_ARR2], __ATOMIC_ACQUIRE,
                               __HIP_MEMORY_SCOPE_AGENT) < (uint32_t)NBLK)
        __builtin_amdgcn_s_sleep(2);
    }
    __syncthreads();
    int cls = b;
    uint32_t cnt = __hip_atomic_load(&ws[cls == 0 ? OFF_CNTF : OFF_CNTB],
                                     __ATOMIC_RELAXED,
                                     __HIP_MEMORY_SCOPE_AGENT);
    uint32_t C = cnt < CAND_CAP ? cnt : CAND_CAP;
    uint32_t need = ssel[cls * 4 + 2];
    const uint64_t* cand = (cls == 0) ? candf : candb;
    for (uint32_t i = tid; i < C; i += 256)
      sbuf[i] = __hip_atomic_load(&cand[i], __ATOMIC_RELAXED,
                                  __HIP_MEMORY_SCOPE_AGENT);
    __syncthreads();
    for (uint32_t i = tid; i < C; i += 256) {
      uint64_t k = sbuf[i];
      uint32_t r = 0;
      for (uint32_t j = 0; j < C; j++) r += (sbuf[j] < k) ? 1u : 0u;
      if (r < need) {                    // keys unique -> exactly `need` kept
        uint32_t n = (uint32_t)(k & 0xFFFFFu);
        uint32_t aa = n % 9u, hw = n / 9u;
        uint32_t t = aa * HW + hw;
        if (cls == 0) {
          out_lab[t] = 1.0f;
          #pragma unroll
          for (int j = 0; j < 4; j++) out_wts[(aa * 4 + j) * HW + hw] = inv;
        } else {
          out_lab[t] = 0.0f;
        }
      }
    }
  }
}

extern "C" void kernel_launch(void* const* d_in, const int* in_sizes, int n_in,
                              void* d_out, int out_size, void* d_ws,
                              size_t ws_size, hipStream_t stream) {
  const float* gt  = (const float*)d_in[1];
  const int*   imw = (const int*)d_in[2];
  const int*   imh = (const int*)d_in[3];
  float* out      = (float*)d_out;
  float* out_lab  = out;                   // 589824
  float* out_adj  = out + N_ANCH;          // 4*589824
  float* out_wts  = out + 5 * N_ANCH;      // 4*589824
  uint32_t* ws = (uint32_t*)d_ws;

  uint32_t kf0, kf1, kb0, kb1;
  tf2x32(0u, 42u, 0u, 0u, &kf0, &kf1);
  tf2x32(0u, 42u, 0u, 1u, &kb0, &kb1);

  hipLaunchKernelGGL(k_pre, dim3(NG * 8), dim3(256), 0, stream, gt, imw, imh,
                     ws);
  hipLaunchKernelGGL(k_fat, dim3(NBLK), dim3(256), 0, stream, gt, imw, imh,
                     out_lab, out_adj, out_wts, ws, kf0, kf1, kb0, kb1);
}

// Round 5
// 189.880 us; speedup vs baseline: 1.0233x; 1.0233x over previous
//
#include <hip/hip_runtime.h>
#include <stdint.h>

// ===========================================================================
// AnchorDataGenerator (Faster R-CNN anchor target layer), MI355X / gfx950
// Round 5: revert to split kernels (round-4 global barrier was straggler-
// bound); attack k_main latency + launch count.
//  - k_pre: zero ctrl region + windowed per-gt max IoU (512 blocks).
//  - k_main: 1152 blocks x 128 thr (anchor-type x 4-row group x 2 col halves).
//    Wave 0 compacts surviving gts into dense LDS (float4 box + float2
//    (area,gmax) + rowmask) -> hot loop is counter-indexed ds_read_b128,
//    no ffsll->LDS dependent chain. NBIN=512. Last block does select.
//  - k_emit: 576 blocks x 256 thr, 4 anchors/thread, uint4/float4 I/O;
//    last block (done-counter) does the exact O(C^2) boundary-bin fixup.
// All IoU math bit-exact vs reference (contract off, IEEE div, same order).
// ===========================================================================

#define NUM_A 9
#define HW 65536
#define N_ANCH 589824
#define NG 64
#define CAPK 128u
#define NBIN 512
#define BIN_SHIFT 14
#define CAND_CAP 4096
#define NBLK_MAIN 1152
#define NBLK_EMIT 576

#define LAB_BG 0u
#define LAB_FG 1u
#define LAB_IGN 2u

// workspace layout (u32 units); total 607760 u32 ~= 2.43 MB
#define OFF_GMAX8 0                        // 64 gts x 8 slices
#define OFF_HF    512
#define OFF_HB    (OFF_HF + NBIN)          // 1024
#define OFF_CNTF  (OFF_HF + 2*NBIN)        // 1536
#define OFF_CNTB  (OFF_CNTF + 1)           // 1537
#define OFF_DONE1 (OFF_CNTF + 2)           // 1538 (k_main select)
#define OFF_DONE2 (OFF_CNTF + 3)           // 1539 (k_emit fixup)
#define OFF_SEL   (OFF_CNTF + 8)           // 1544..1551: {bin,below,need,K} x2
#define OFF_CANDF 1552                     // even -> 8B aligned u64 keys
#define OFF_CANDB (OFF_CANDF + 2*CAND_CAP) // 9744
#define OFF_LABM  (OFF_CANDB + 2*CAND_CAP) // 17936
#define ZERO_BEG  OFF_HF
#define ZERO_END  OFF_CANDF
#define NZ        (ZERO_END - ZERO_BEG)    // 1040 words

__constant__ float BA[NUM_A][4] = {
  { -84.f,  -40.f,  99.f,  55.f}, {-176.f,  -88.f, 191.f, 103.f},
  {-360.f, -184.f, 375.f, 199.f}, { -56.f,  -56.f,  71.f,  71.f},
  {-120.f, -120.f, 135.f, 135.f}, {-248.f, -248.f, 263.f, 263.f},
  { -36.f,  -80.f,  51.f,  95.f}, { -80.f, -168.f,  95.f, 183.f},
  {-168.f, -344.f, 183.f, 359.f}};

__host__ __device__ static inline void tf2x32(uint32_t k0, uint32_t k1,
                                              uint32_t x0, uint32_t x1,
                                              uint32_t* o0, uint32_t* o1) {
  const uint32_t ks2 = k0 ^ k1 ^ 0x1BD11BDAu;
#define TF_R(r) { x0 += x1; x1 = (x1 << (r)) | (x1 >> (32 - (r))); x1 ^= x0; }
  x0 += k0; x1 += k1;
  TF_R(13) TF_R(15) TF_R(26) TF_R(6)
  x0 += k1;  x1 += ks2 + 1u;
  TF_R(17) TF_R(29) TF_R(16) TF_R(24)
  x0 += ks2; x1 += k0 + 2u;
  TF_R(13) TF_R(15) TF_R(26) TF_R(6)
  x0 += k0;  x1 += k1 + 3u;
  TF_R(17) TF_R(29) TF_R(16) TF_R(24)
  x0 += k1;  x1 += ks2 + 4u;
  TF_R(13) TF_R(15) TF_R(26) TF_R(6)
  x0 += ks2; x1 += k0 + 5u;
#undef TF_R
  *o0 = x0; *o1 = x1;
}

__device__ static inline uint32_t mant_of(uint32_t k0, uint32_t k1, uint32_t n) {
  uint32_t o0, o1;
  tf2x32(k0, k1, 0u, n, &o0, &o1);   // partitionable: counter = (hi=0, lo=n)
  return (o0 ^ o1) >> 9;             // 23-bit mantissa
}

// IoU in the reference's exact fp32 op order (contraction OFF).
__device__ static inline float iou1(float a0, float a1, float a2, float a3,
                                    float aarea, float g0, float g1, float g2,
                                    float g3, float garea) {
  #pragma clang fp contract(off)
  float ix1 = fmaxf(a0, g0);
  float iy1 = fmaxf(a1, g1);
  float ix2 = fminf(a2, g2);
  float iy2 = fminf(a3, g3);
  float iw = ix2 - ix1 + 1.0f;
  float ih = iy2 - iy1 + 1.0f;
  float inter = (iw > 0.0f && ih > 0.0f) ? iw * ih : 0.0f;
  float den = aarea + garea - inter;
  return inter / den;                  // IEEE-rounded div
}

// ---- k_pre: zero ctrl region + per-gt windowed max IoU (8 slices/gt) ------
__global__ __launch_bounds__(256) void k_pre(const float* __restrict__ gt,
                                             const int* __restrict__ imw_p,
                                             const int* __restrict__ imh_p,
                                             uint32_t* __restrict__ ws) {
  #pragma clang fp contract(off)
  int tid = threadIdx.x;
  int b = blockIdx.x;
  int gid = b * 256 + tid;
  if (gid < NZ) ws[ZERO_BEG + gid] = 0u;

  int g = b >> 3, sl = b & 7;
  float g0 = gt[g*4+0], g1 = gt[g*4+1], g2 = gt[g*4+2], g3 = gt[g*4+3];
  float gw = g2 - g0 + 1.0f, gh = g3 - g1 + 1.0f;
  float ga = (gw > 0.0f && gh > 0.0f) ? gw * gh : 0.0f;
  float imw = (float)imw_p[0], imh = (float)imh_p[0];

  float mx = 0.0f;   // g_max >= 0 always (some valid anchor exists)
  for (int a = 0; a < NUM_A; a++) {
    float b0 = BA[a][0], b1 = BA[a][1], b2 = BA[a][2], b3 = BA[a][3];
    int wlo = max(0,   (int)floorf((g0 - 1.0f - b2) * 0.0625f));
    int whi = min(255, (int)ceilf ((g2 + 1.0f - b0) * 0.0625f));
    int hlo = max(0,   (int)floorf((g1 - 1.0f - b3) * 0.0625f));
    int hhi = min(255, (int)ceilf ((g3 + 1.0f - b1) * 0.0625f));
    int wx = whi - wlo + 1, wy = hhi - hlo + 1;
    if (wx <= 0 || wy <= 0) continue;
    int tot = wx * wy;
    for (int idx = sl * 256 + tid; idx < tot; idx += 2048) {
      int h = hlo + idx / wx, w = wlo + idx % wx;
      float sx = (float)(w << 4), sy = (float)(h << 4);
      float x1 = b0 + sx, y1 = b1 + sy, x2 = b2 + sx, y2 = b3 + sy;
      float aw = x2 - x1 + 1.0f, ah = y2 - y1 + 1.0f;
      float aarea = aw * ah;
      bool vld = (x1 >= 0.0f) && (y1 >= 0.0f) && (x2 < imw) && (y2 < imh);
      float o = iou1(x1, y1, x2, y2, aarea, g0, g1, g2, g3, ga);
      if (vld) mx = fmaxf(mx, o);
    }
  }
  #pragma unroll
  for (int s = 32; s >= 1; s >>= 1) mx = fmaxf(mx, __shfl_xor(mx, s, 64));
  __shared__ float wmax[4];
  if ((tid & 63) == 0) wmax[tid >> 6] = mx;
  __syncthreads();
  if (tid == 0) {
    float m = fmaxf(fmaxf(wmax[0], wmax[1]), fmaxf(wmax[2], wmax[3]));
    ws[OFF_GMAX8 + g * 8 + sl] = __float_as_uint(m);
  }
}

// ---- k_main: labels/adj/mantissa/hist; last block does select -------------
__global__ __launch_bounds__(128) void k_main(const float* __restrict__ gt,
                                              const int* __restrict__ imw_p,
                                              const int* __restrict__ imh_p,
                                              float* __restrict__ out_adj,
                                              uint32_t* __restrict__ ws,
                                              uint32_t kf0, uint32_t kf1,
                                              uint32_t kb0, uint32_t kb1) {
  #pragma clang fp contract(off)
  __shared__ float4 cg4[NG];
  __shared__ float2 cgam[NG];               // (g_area, g_max)
  __shared__ uint32_t crow[NG];             // (rowmask<<8) | g
  __shared__ uint32_t sh[2 * NBIN];         // 4 KB histograms / scan scratch
  __shared__ int scnt, sAnyZero, sLast;
  int tid = threadIdx.x;
  {
    uint4* sh4 = (uint4*)sh;
    sh4[tid] = make_uint4(0, 0, 0, 0);
    sh4[tid + 128] = make_uint4(0, 0, 0, 0);
  }

  int b = blockIdx.x;
  int a = b >> 7, rem = b & 127;
  int hb = (rem >> 1) << 2;                 // 4 rows hb..hb+3
  int wbase = (rem & 1) << 7;               // column half
  float BA0 = BA[a][0], BA1 = BA[a][1], BA2 = BA[a][2], BA3 = BA[a][3];

  if (tid == 0) { sAnyZero = 0; scnt = 0; }
  if (tid < NG) {                           // wave 0: compact surviving gts
    int g = tid;
    const float4 g4 = ((const float4*)gt)[g];
    float gw = g4.z - g4.x + 1.0f, gh = g4.w - g4.y + 1.0f;
    float ga = (gw > 0.0f && gh > 0.0f) ? gw * gh : 0.0f;
    uint32_t mm = 0u;
    #pragma unroll
    for (int j = 0; j < 8; j++) mm = max(mm, ws[OFF_GMAX8 + g * 8 + j]);
    if (mm == 0u) atomicOr(&sAnyZero, 1);
    uint32_t rb = 0u;
    #pragma unroll
    for (int r = 0; r < 4; r++) {
      float sy = (float)((hb + r) << 4);
      float ihp = fminf(BA3 + sy, g4.w) - fmaxf(BA1 + sy, g4.y) + 1.0f;
      if (ihp > 0.0f) rb |= (1u << r);
    }
    bool pred = (rb != 0u);
    unsigned long long mk = __ballot(pred);
    int idx = __popcll(mk & ((1ull << g) - 1ull));
    if (pred) {
      cg4[idx] = g4;
      cgam[idx] = make_float2(ga, __uint_as_float(mm));
      crow[idx] = (rb << 8) | (uint32_t)g;
    }
    if (g == 0) scnt = __popcll(mk);
  }
  __syncthreads();

  float imw = (float)imw_p[0], imh = (float)imh_p[0];
  int w = wbase + tid;
  float sx = (float)(w << 4);
  float A0 = BA0 + sx, A2 = BA2 + sx;
  float aw = A2 - A0 + 1.0f;
  float A1v[4], A3v[4];
  #pragma unroll
  for (int r = 0; r < 4; r++) {
    float sy = (float)((hb + r) << 4);
    A1v[r] = BA1 + sy; A3v[r] = BA3 + sy;
  }
  float ah = A3v[0] - A1v[0] + 1.0f;
  float aarea = aw * ah;                    // exact ints -> bit-exact
  bool xv = (A0 >= 0.0f) && (A2 < imw);

  int cnt = scnt;
  float amaxv[4] = {0.f, 0.f, 0.f, 0.f};
  int bgv[4] = {0, 0, 0, 0};
  uint32_t afv = 0u;
  for (int i = 0; i < cnt; i++) {           // ascending g -> first-max argmax
    float4 g4 = cg4[i];
    float iw = fminf(A2, g4.z) - fmaxf(A0, g4.x) + 1.0f;
    if (!__any(iw > 0.0f)) continue;
    float2 gam = cgam[i];
    uint32_t rbg = crow[i];
    if (iw > 0.0f) {
      int g = (int)(rbg & 0xFFu);
      uint32_t rb = rbg >> 8;
      float base = aarea + gam.x;
      float gm = gam.y;
      #pragma unroll
      for (int r = 0; r < 4; r++) {
        if ((rb >> r) & 1u) {               // row overlaps in y (ih>0)
          float ih = fminf(A3v[r], g4.w) - fmaxf(A1v[r], g4.y) + 1.0f;
          float inter = iw * ih;
          float o = inter / (base - inter); // IEEE
          if (o > amaxv[r]) { amaxv[r] = o; bgv[r] = g; }
          if (o == gm) afv |= (1u << r);
        }
      }
    }
  }

  bool anyZ = (sAnyZero != 0);
  #pragma unroll
  for (int r = 0; r < 4; r++) {
    int hw = (hb + r) * 256 + w;
    bool valid = xv && (A1v[r] >= 0.0f) && (A3v[r] < imh);
    float amax = amaxv[r];
    bool anyfg = (((afv >> r) & 1u) || anyZ) && valid;
    uint32_t lab;
    if (!valid)                       lab = LAB_IGN;
    else if (anyfg || amax >= 0.7f)   lab = LAB_FG;
    else if (amax < 0.3f)             lab = LAB_BG;
    else                              lab = LAB_IGN;

    float adj0 = 0.f, adj1 = 0.f, adj2 = 0.f, adj3 = 0.f;
    if (valid) {
      int bg = bgv[r];
      float4 G = cnt ? cg4[0] : make_float4(0.f, 0.f, 0.f, 0.f);
      // need original-indexed gt: bgv holds original g; load from global
      float G0 = gt[bg*4+0], G1 = gt[bg*4+1], G2 = gt[bg*4+2], G3 = gt[bg*4+3];
      (void)G;
      float ax = (A2 + A0) * 0.5f, ay = (A3v[r] + A1v[r]) * 0.5f;
      float gwm = G2 - G0 + 1.0f, ghm = G3 - G1 + 1.0f;
      float gx = (G2 + G0) * 0.5f, gy = (G3 + G1) * 0.5f;
      adj0 = (gx - ax) / aw;
      adj1 = (gy - ay) / ah;
      adj2 = logf(gwm / aw);
      adj3 = logf(ghm / ah);
    }
    int c4 = a * 4;
    out_adj[(c4 + 0) * HW + hw] = adj0;
    out_adj[(c4 + 1) * HW + hw] = adj1;
    out_adj[(c4 + 2) * HW + hw] = adj2;
    out_adj[(c4 + 3) * HW + hw] = adj3;

    uint32_t m = 0u;
    uint32_t n = (uint32_t)(hw * 9 + a);    // original anchor index (tie-break)
    if (lab != LAB_IGN) {
      uint32_t kk0 = (lab == LAB_FG) ? kf0 : kb0;
      uint32_t kk1 = (lab == LAB_FG) ? kf1 : kb1;
      m = mant_of(kk0, kk1, n);
      atomicAdd(&sh[((lab == LAB_FG) ? 0 : NBIN) + (m >> BIN_SHIFT)], 1u);
    }
    ws[OFF_LABM + a * HW + hw] = (lab << 24) | m;
  }

  __syncthreads();
  for (int i = tid; i < 2 * NBIN; i += 128) {
    uint32_t v = sh[i];
    if (v) atomicAdd(&ws[OFF_HF + i], v);
  }
  __syncthreads();
  if (tid == 0) {
    uint32_t prev = __hip_atomic_fetch_add(&ws[OFF_DONE1], 1u,
                                           __ATOMIC_ACQ_REL,
                                           __HIP_MEMORY_SCOPE_AGENT);
    sLast = (prev == NBLK_MAIN - 1u) ? 1 : 0;
  }
  __syncthreads();
  if (sLast) {
    for (int cls = 0; cls < 2; cls++) {
      uint32_t* hist = ws + (cls ? OFF_HB : OFF_HF);
      uint32_t* sel = ws + OFF_SEL + cls * 4;
      uint32_t loc[4], s = 0;
      #pragma unroll
      for (int j = 0; j < 4; j++) {
        loc[j] = __hip_atomic_load(&hist[tid * 4 + j], __ATOMIC_RELAXED,
                                   __HIP_MEMORY_SCOPE_AGENT);
        s += loc[j];
      }
      __syncthreads();
      sh[tid] = s; __syncthreads();
      for (int off = 1; off < 128; off <<= 1) {
        uint32_t v = (tid >= off) ? sh[tid - off] : 0u;
        __syncthreads();
        sh[tid] += v;
        __syncthreads();
      }
      uint32_t total = sh[127];
      uint32_t K = total < CAPK ? total : CAPK;
      if (tid == 0) {
        sel[3] = K;
        if (K == 0u) { sel[0] = 0xFFFFFFFFu; sel[1] = 0u; sel[2] = 0u; }
      }
      if (K > 0u) {
        uint32_t myC = sh[tid], pvC = (tid == 0) ? 0u : sh[tid - 1];
        if (myC >= K && pvC < K) {          // exactly one thread
          uint32_t cum = pvC; int bb2 = tid * 4;
          for (int j = 0; j < 4; j++) {
            if (cum + loc[j] >= K) { bb2 = tid * 4 + j; break; }
            cum += loc[j];
          }
          sel[0] = (uint32_t)bb2; sel[1] = cum; sel[2] = K - cum;
        }
      }
      __syncthreads();
    }
  }
}

// ---- k_emit: labels/wts (4 anchors/thread) + candidates; last block fixup -
__global__ __launch_bounds__(256) void k_emit(float* __restrict__ out_lab,
                                              float* __restrict__ out_wts,
                                              uint32_t* __restrict__ ws) {
  __shared__ uint64_t sc[CAND_CAP];          // 32 KB (fixup staging)
  __shared__ int sLast;
  int tid = threadIdx.x;
  int t4 = (blockIdx.x * 256 + tid) * 4;     // 4 consecutive hw, same a
  int a = t4 >> 16, hw0 = t4 & 65535;
  uint4 lm4 = *(const uint4*)&ws[OFF_LABM + t4];
  uint32_t bf = ws[OFF_SEL + 0], bbs = ws[OFF_SEL + 4];
  uint32_t Kf = ws[OFF_SEL + 3], Kb = ws[OFF_SEL + 7];
  float inv = 1.0f / (float)(Kf + Kb);       // 1/num_ni
  uint64_t* candf = (uint64_t*)(ws + OFF_CANDF);
  uint64_t* candb = (uint64_t*)(ws + OFF_CANDB);

  float lv[4], wv[4];
  uint32_t lms[4] = {lm4.x, lm4.y, lm4.z, lm4.w};
  #pragma unroll
  for (int j = 0; j < 4; j++) {
    uint32_t lab = lms[j] >> 24;
    uint32_t m = lms[j] & 0x7FFFFFu;
    uint32_t n = (uint32_t)((hw0 + j) * 9 + a);
    float outv = 2.0f, wvv = 0.0f;
    if (lab == LAB_FG) {
      uint32_t bn = m >> BIN_SHIFT;
      if (bn < bf) { outv = 1.0f; wvv = inv; }
      else if (bn == bf) {
        uint32_t idx = atomicAdd(&ws[OFF_CNTF], 1u);
        if (idx < CAND_CAP) candf[idx] = ((uint64_t)m << 20) | (uint64_t)n;
      }
    } else if (lab == LAB_BG) {
      uint32_t bn = m >> BIN_SHIFT;
      if (bn < bbs) { outv = 0.0f; }
      else if (bn == bbs) {
        uint32_t idx = atomicAdd(&ws[OFF_CNTB], 1u);
        if (idx < CAND_CAP) candb[idx] = ((uint64_t)m << 20) | (uint64_t)n;
      }
    }
    lv[j] = outv; wv[j] = wvv;
  }
  *(float4*)&out_lab[t4] = make_float4(lv[0], lv[1], lv[2], lv[3]);
  float4 wq = make_float4(wv[0], wv[1], wv[2], wv[3]);
  int c4 = a * 4;
  *(float4*)&out_wts[(c4 + 0) * HW + hw0] = wq;
  *(float4*)&out_wts[(c4 + 1) * HW + hw0] = wq;
  *(float4*)&out_wts[(c4 + 2) * HW + hw0] = wq;
  *(float4*)&out_wts[(c4 + 3) * HW + hw0] = wq;

  __syncthreads();
  if (tid == 0) {
    uint32_t prev = __hip_atomic_fetch_add(&ws[OFF_DONE2], 1u,
                                           __ATOMIC_ACQ_REL,
                                           __HIP_MEMORY_SCOPE_AGENT);
    sLast = (prev == NBLK_EMIT - 1u) ? 1 : 0;
  }
  __syncthreads();
  if (sLast) {
    for (int cls = 0; cls < 2; cls++) {
      uint32_t cnt = __hip_atomic_load(&ws[cls == 0 ? OFF_CNTF : OFF_CNTB],
                                       __ATOMIC_RELAXED,
                                       __HIP_MEMORY_SCOPE_AGENT);
      uint32_t C = cnt < CAND_CAP ? cnt : CAND_CAP;
      uint32_t need = ws[OFF_SEL + cls * 4 + 2];
      const uint64_t* cand = (cls == 0) ? candf : candb;
      for (uint32_t i = tid; i < C; i += 256)
        sc[i] = __hip_atomic_load(&cand[i], __ATOMIC_RELAXED,
                                  __HIP_MEMORY_SCOPE_AGENT);
      __syncthreads();
      for (uint32_t i = tid; i < C; i += 256) {
        uint64_t k = sc[i];
        uint32_t r = 0;
        for (uint32_t j = 0; j < C; j++) r += (sc[j] < k) ? 1u : 0u;
        if (r < need) {                    // keys unique -> exactly need kept
          uint32_t n = (uint32_t)(k & 0xFFFFFu);
          uint32_t aa = n % 9u, hw = n / 9u;
          uint32_t t = aa * HW + hw;
          if (cls == 0) {
            out_lab[t] = 1.0f;
            #pragma unroll
            for (int j = 0; j < 4; j++) out_wts[(aa * 4 + j) * HW + hw] = inv;
          } else {
            out_lab[t] = 0.0f;
          }
        }
      }
      __syncthreads();
    }
  }
}

extern "C" void kernel_launch(void* const* d_in, const int* in_sizes, int n_in,
                              void* d_out, int out_size, void* d_ws,
                              size_t ws_size, hipStream_t stream) {
  const float* gt  = (const float*)d_in[1];
  const int*   imw = (const int*)d_in[2];
  const int*   imh = (const int*)d_in[3];
  float* out      = (float*)d_out;
  float* out_lab  = out;                   // 589824
  float* out_adj  = out + N_ANCH;          // 4*589824
  float* out_wts  = out + 5 * N_ANCH;      // 4*589824
  uint32_t* ws = (uint32_t*)d_ws;          // ~2.43 MB used

  uint32_t kf0, kf1, kb0, kb1;
  tf2x32(0u, 42u, 0u, 0u, &kf0, &kf1);
  tf2x32(0u, 42u, 0u, 1u, &kb0, &kb1);

  hipLaunchKernelGGL(k_pre, dim3(NG * 8), dim3(256), 0, stream, gt, imw, imh,
                     ws);
  hipLaunchKernelGGL(k_main, dim3(NBLK_MAIN), dim3(128), 0, stream, gt, imw,
                     imh, out_adj, ws, kf0, kf1, kb0, kb1);
  hipLaunchKernelGGL(k_emit, dim3(NBLK_EMIT), dim3(256), 0, stream, out_lab,
                     out_wts, ws);
}

// Round 6
// 110.258 us; speedup vs baseline: 1.7623x; 1.7221x over previous
//
#include <hip/hip_runtime.h>
#include <stdint.h>

// ===========================================================================
// AnchorDataGenerator (Faster R-CNN anchor target layer), MI355X / gfx950
// Round 6: R3 base (102.5 us known-good) + two isolated fixes:
//  - k_main: wave-0 compacts y-surviving gts into dense LDS records ->
//    counter-indexed hot loop (no ffsll->LDS dependent chain). Everything
//    else identical to R3 (576 blocks x 256 thr, NBIN=2048, last-block
//    select via done-counter).
//  - k_emit: 4 anchors/thread (uint4/float4 I/O) + WAVE-AGGREGATED boundary
//    candidate push (one atomicAdd per wave per class; R5's per-thread
//    same-address device atomics with used return value serialized at L2).
//  - k_fixup: separate 2-block kernel (C~215/class, LDS-staged O(C^2) rank).
// All IoU math bit-exact vs reference (contract off, IEEE div, same order).
// ===========================================================================

#define NUM_A 9
#define HW 65536
#define N_ANCH 589824
#define NG 64
#define CAPK 128u
#define NBIN 2048
#define BIN_SHIFT 12
#define CAND_CAP 4096
#define NBLK_MAIN 576
#define NBLK_EMIT 576

#define LAB_BG 0u
#define LAB_FG 1u
#define LAB_IGN 2u

// workspace layout (u32 units); total ~610832 u32 ~= 2.44 MB
#define OFF_GMAX8 0                        // 64 gts x 8 slices
#define OFF_HF    512
#define OFF_HB    (OFF_HF + NBIN)          // 2560
#define OFF_CNTF  (OFF_HF + 2*NBIN)        // 4608
#define OFF_CNTB  (OFF_CNTF + 1)           // 4609
#define OFF_DONE1 (OFF_CNTF + 2)           // 4610 (k_main select)
#define OFF_SEL   (OFF_CNTF + 8)           // 4616..4623: {bin,below,need,K} x2
#define OFF_CANDF 4624                     // 8B aligned u64 keys
#define OFF_CANDB (OFF_CANDF + 2*CAND_CAP) // 12816
#define OFF_LABM  (OFF_CANDB + 2*CAND_CAP) // 21008
#define ZERO_BEG  OFF_HF
#define ZERO_END  OFF_CANDF
#define NZ        (ZERO_END - ZERO_BEG)    // 4112 words

__constant__ float BA[NUM_A][4] = {
  { -84.f,  -40.f,  99.f,  55.f}, {-176.f,  -88.f, 191.f, 103.f},
  {-360.f, -184.f, 375.f, 199.f}, { -56.f,  -56.f,  71.f,  71.f},
  {-120.f, -120.f, 135.f, 135.f}, {-248.f, -248.f, 263.f, 263.f},
  { -36.f,  -80.f,  51.f,  95.f}, { -80.f, -168.f,  95.f, 183.f},
  {-168.f, -344.f, 183.f, 359.f}};

__host__ __device__ static inline void tf2x32(uint32_t k0, uint32_t k1,
                                              uint32_t x0, uint32_t x1,
                                              uint32_t* o0, uint32_t* o1) {
  const uint32_t ks2 = k0 ^ k1 ^ 0x1BD11BDAu;
#define TF_R(r) { x0 += x1; x1 = (x1 << (r)) | (x1 >> (32 - (r))); x1 ^= x0; }
  x0 += k0; x1 += k1;
  TF_R(13) TF_R(15) TF_R(26) TF_R(6)
  x0 += k1;  x1 += ks2 + 1u;
  TF_R(17) TF_R(29) TF_R(16) TF_R(24)
  x0 += ks2; x1 += k0 + 2u;
  TF_R(13) TF_R(15) TF_R(26) TF_R(6)
  x0 += k0;  x1 += k1 + 3u;
  TF_R(17) TF_R(29) TF_R(16) TF_R(24)
  x0 += k1;  x1 += ks2 + 4u;
  TF_R(13) TF_R(15) TF_R(26) TF_R(6)
  x0 += ks2; x1 += k0 + 5u;
#undef TF_R
  *o0 = x0; *o1 = x1;
}

__device__ static inline uint32_t mant_of(uint32_t k0, uint32_t k1, uint32_t n) {
  uint32_t o0, o1;
  tf2x32(k0, k1, 0u, n, &o0, &o1);   // partitionable: counter = (hi=0, lo=n)
  return (o0 ^ o1) >> 9;             // 23-bit mantissa
}

// IoU in the reference's exact fp32 op order (contraction OFF).
__device__ static inline float iou1(float a0, float a1, float a2, float a3,
                                    float aarea, float g0, float g1, float g2,
                                    float g3, float garea) {
  #pragma clang fp contract(off)
  float ix1 = fmaxf(a0, g0);
  float iy1 = fmaxf(a1, g1);
  float ix2 = fminf(a2, g2);
  float iy2 = fminf(a3, g3);
  float iw = ix2 - ix1 + 1.0f;
  float ih = iy2 - iy1 + 1.0f;
  float inter = (iw > 0.0f && ih > 0.0f) ? iw * ih : 0.0f;
  float den = aarea + garea - inter;
  return inter / den;                  // IEEE-rounded div
}

// ---- k_pre: zero ctrl region + per-gt windowed max IoU (8 slices/gt) ------
__global__ __launch_bounds__(256) void k_pre(const float* __restrict__ gt,
                                             const int* __restrict__ imw_p,
                                             const int* __restrict__ imh_p,
                                             uint32_t* __restrict__ ws) {
  #pragma clang fp contract(off)
  int tid = threadIdx.x;
  int b = blockIdx.x;
  int gid = b * 256 + tid;
  if (gid < NZ) ws[ZERO_BEG + gid] = 0u;

  int g = b >> 3, sl = b & 7;
  float g0 = gt[g*4+0], g1 = gt[g*4+1], g2 = gt[g*4+2], g3 = gt[g*4+3];
  float gw = g2 - g0 + 1.0f, gh = g3 - g1 + 1.0f;
  float ga = (gw > 0.0f && gh > 0.0f) ? gw * gh : 0.0f;
  float imw = (float)imw_p[0], imh = (float)imh_p[0];

  float mx = 0.0f;   // g_max >= 0 always (some valid anchor exists)
  for (int a = 0; a < NUM_A; a++) {
    float b0 = BA[a][0], b1 = BA[a][1], b2 = BA[a][2], b3 = BA[a][3];
    int wlo = max(0,   (int)floorf((g0 - 1.0f - b2) * 0.0625f));
    int whi = min(255, (int)ceilf ((g2 + 1.0f - b0) * 0.0625f));
    int hlo = max(0,   (int)floorf((g1 - 1.0f - b3) * 0.0625f));
    int hhi = min(255, (int)ceilf ((g3 + 1.0f - b1) * 0.0625f));
    int wx = whi - wlo + 1, wy = hhi - hlo + 1;
    if (wx <= 0 || wy <= 0) continue;
    int tot = wx * wy;
    for (int idx = sl * 256 + tid; idx < tot; idx += 2048) {
      int h = hlo + idx / wx, w = wlo + idx % wx;
      float sx = (float)(w << 4), sy = (float)(h << 4);
      float x1 = b0 + sx, y1 = b1 + sy, x2 = b2 + sx, y2 = b3 + sy;
      float aw = x2 - x1 + 1.0f, ah = y2 - y1 + 1.0f;
      float aarea = aw * ah;
      bool vld = (x1 >= 0.0f) && (y1 >= 0.0f) && (x2 < imw) && (y2 < imh);
      float o = iou1(x1, y1, x2, y2, aarea, g0, g1, g2, g3, ga);
      if (vld) mx = fmaxf(mx, o);
    }
  }
  #pragma unroll
  for (int s = 32; s >= 1; s >>= 1) mx = fmaxf(mx, __shfl_xor(mx, s, 64));
  __shared__ float wmax[4];
  if ((tid & 63) == 0) wmax[tid >> 6] = mx;
  __syncthreads();
  if (tid == 0) {
    float m = fmaxf(fmaxf(wmax[0], wmax[1]), fmaxf(wmax[2], wmax[3]));
    ws[OFF_GMAX8 + g * 8 + sl] = __float_as_uint(m);
  }
}

// ---- k_main: labels/adj/mantissa/hist; last block does select -------------
__global__ __launch_bounds__(256) void k_main(const float* __restrict__ gt,
                                              const int* __restrict__ imw_p,
                                              const int* __restrict__ imh_p,
                                              float* __restrict__ out_adj,
                                              uint32_t* __restrict__ ws,
                                              uint32_t kf0, uint32_t kf1,
                                              uint32_t kb0, uint32_t kb1) {
  #pragma clang fp contract(off)
  __shared__ float4 sgt4[NG];               // original-indexed (epilogue)
  __shared__ float4 cg4[NG];                // compacted boxes
  __shared__ float2 cgam[NG];               // compacted (g_area, g_max)
  __shared__ uint32_t crow[NG];             // (rowmask<<8) | original g
  __shared__ uint32_t sh[2 * NBIN];         // 16 KB hist / scan scratch
  __shared__ int scnt, sAnyZero, sLast;
  int tid = threadIdx.x;
  {
    uint4* sh4 = (uint4*)sh;
    #pragma unroll
    for (int k = 0; k < 4; k++) sh4[tid + k * 256] = make_uint4(0, 0, 0, 0);
  }

  int b = blockIdx.x;
  int a = b >> 6, hb = (b & 63) << 2;       // anchor type, 4 rows hb..hb+3
  float BA0 = BA[a][0], BA1 = BA[a][1], BA2 = BA[a][2], BA3 = BA[a][3];

  if (tid < NG) {                           // wave 0: load + compact gts
    int g = tid;
    const float4 g4 = ((const float4*)gt)[g];
    sgt4[g] = g4;
    float gw = g4.z - g4.x + 1.0f, gh = g4.w - g4.y + 1.0f;
    float ga = (gw > 0.0f && gh > 0.0f) ? gw * gh : 0.0f;
    uint4 q0 = *(const uint4*)&ws[OFF_GMAX8 + g * 8];
    uint4 q1 = *(const uint4*)&ws[OFF_GMAX8 + g * 8 + 4];
    uint32_t mm = max(max(max(q0.x, q0.y), max(q0.z, q0.w)),
                      max(max(q1.x, q1.y), max(q1.z, q1.w)));
    uint32_t rb = 0u;
    #pragma unroll
    for (int r = 0; r < 4; r++) {
      float sy = (float)((hb + r) << 4);
      float ihp = fminf(BA3 + sy, g4.w) - fmaxf(BA1 + sy, g4.y) + 1.0f;
      if (ihp > 0.0f) rb |= (1u << r);
    }
    unsigned long long zb = __ballot(mm == 0u);
    bool pred = (rb != 0u);
    unsigned long long mk = __ballot(pred);
    int idx = __popcll(mk & ((1ull << g) - 1ull));
    if (pred) {
      cg4[idx] = g4;
      cgam[idx] = make_float2(ga, __uint_as_float(mm));
      crow[idx] = (rb << 8) | (uint32_t)g;
    }
    if (g == 0) {
      scnt = __popcll(mk);
      sAnyZero = (zb != 0ull) ? 1 : 0;      // degenerate g_max == 0
    }
  }
  __syncthreads();

  float imw = (float)imw_p[0], imh = (float)imh_p[0];
  int w = tid;
  float sx = (float)(w << 4);
  float A0 = BA0 + sx, A2 = BA2 + sx;
  float aw = A2 - A0 + 1.0f;
  float A1v[4], A3v[4];
  #pragma unroll
  for (int r = 0; r < 4; r++) {
    float sy = (float)((hb + r) << 4);
    A1v[r] = BA1 + sy; A3v[r] = BA3 + sy;
  }
  float ah = A3v[0] - A1v[0] + 1.0f;
  float aarea = aw * ah;                    // exact ints -> bit-exact
  bool xv = (A0 >= 0.0f) && (A2 < imw);

  int cnt = scnt;
  float amaxv[4] = {0.f, 0.f, 0.f, 0.f};
  int bgv[4] = {0, 0, 0, 0};
  uint32_t afv = 0u;
  for (int i = 0; i < cnt; i++) {           // ascending g -> first-max argmax
    float4 g4 = cg4[i];
    float iw = fminf(A2, g4.z) - fmaxf(A0, g4.x) + 1.0f;
    if (!__any(iw > 0.0f)) continue;
    float2 gam = cgam[i];
    uint32_t rbg = crow[i];
    if (iw > 0.0f) {
      int g = (int)(rbg & 0xFFu);
      uint32_t rb = rbg >> 8;
      float base = aarea + gam.x;
      float gm = gam.y;
      #pragma unroll
      for (int r = 0; r < 4; r++) {
        if ((rb >> r) & 1u) {               // row overlaps in y (ih>0)
          float ih = fminf(A3v[r], g4.w) - fmaxf(A1v[r], g4.y) + 1.0f;
          float inter = iw * ih;
          float o = inter / (base - inter); // IEEE
          if (o > amaxv[r]) { amaxv[r] = o; bgv[r] = g; }
          if (o == gm) afv |= (1u << r);
        }
      }
    }
  }

  bool anyZ = (sAnyZero != 0);
  #pragma unroll
  for (int r = 0; r < 4; r++) {
    int hw = (hb + r) * 256 + w;
    bool valid = xv && (A1v[r] >= 0.0f) && (A3v[r] < imh);
    float amax = amaxv[r];
    bool anyfg = (((afv >> r) & 1u) || anyZ) && valid;
    uint32_t lab;
    if (!valid)                       lab = LAB_IGN;
    else if (anyfg || amax >= 0.7f)   lab = LAB_FG;
    else if (amax < 0.3f)             lab = LAB_BG;
    else                              lab = LAB_IGN;

    float adj0 = 0.f, adj1 = 0.f, adj2 = 0.f, adj3 = 0.f;
    if (valid) {
      float4 G = sgt4[bgv[r]];
      float ax = (A2 + A0) * 0.5f, ay = (A3v[r] + A1v[r]) * 0.5f;
      float gwm = G.z - G.x + 1.0f, ghm = G.w - G.y + 1.0f;
      float gx = (G.z + G.x) * 0.5f, gy = (G.w + G.y) * 0.5f;
      adj0 = (gx - ax) / aw;
      adj1 = (gy - ay) / ah;
      adj2 = logf(gwm / aw);
      adj3 = logf(ghm / ah);
    }
    int c4 = a * 4;
    out_adj[(c4 + 0) * HW + hw] = adj0;
    out_adj[(c4 + 1) * HW + hw] = adj1;
    out_adj[(c4 + 2) * HW + hw] = adj2;
    out_adj[(c4 + 3) * HW + hw] = adj3;

    uint32_t m = 0u;
    uint32_t n = (uint32_t)(hw * 9 + a);    // original anchor index (tie-break)
    if (lab != LAB_IGN) {
      uint32_t kk0 = (lab == LAB_FG) ? kf0 : kb0;
      uint32_t kk1 = (lab == LAB_FG) ? kf1 : kb1;
      m = mant_of(kk0, kk1, n);
      atomicAdd(&sh[((lab == LAB_FG) ? 0 : NBIN) + (m >> BIN_SHIFT)], 1u);
    }
    ws[OFF_LABM + a * HW + hw] = (lab << 24) | m;
  }

  __syncthreads();
  for (int i = tid; i < 2 * NBIN; i += 256) {
    uint32_t v = sh[i];
    if (v) atomicAdd(&ws[OFF_HF + i], v);
  }
  __syncthreads();
  if (tid == 0) {
    uint32_t prev = __hip_atomic_fetch_add(&ws[OFF_DONE1], 1u,
                                           __ATOMIC_ACQ_REL,
                                           __HIP_MEMORY_SCOPE_AGENT);
    sLast = (prev == NBLK_MAIN - 1u) ? 1 : 0;
  }
  __syncthreads();
  if (sLast) {
    for (int cls = 0; cls < 2; cls++) {
      uint32_t* hist = ws + (cls ? OFF_HB : OFF_HF);
      uint32_t* sel = ws + OFF_SEL + cls * 4;
      uint32_t loc[8], s = 0;
      #pragma unroll
      for (int j = 0; j < 8; j++) {
        loc[j] = __hip_atomic_load(&hist[tid * 8 + j], __ATOMIC_RELAXED,
                                   __HIP_MEMORY_SCOPE_AGENT);
        s += loc[j];
      }
      __syncthreads();
      sh[tid] = s; __syncthreads();
      for (int off = 1; off < 256; off <<= 1) {
        uint32_t v = (tid >= off) ? sh[tid - off] : 0u;
        __syncthreads();
        sh[tid] += v;
        __syncthreads();
      }
      uint32_t total = sh[255];
      uint32_t K = total < CAPK ? total : CAPK;
      if (tid == 0) {
        sel[3] = K;
        if (K == 0u) { sel[0] = 0xFFFFFFFFu; sel[1] = 0u; sel[2] = 0u; }
      }
      if (K > 0u) {
        uint32_t myC = sh[tid], pvC = (tid == 0) ? 0u : sh[tid - 1];
        if (myC >= K && pvC < K) {          // exactly one thread
          uint32_t cum = pvC; int bb2 = tid * 8;
          for (int j = 0; j < 8; j++) {
            if (cum + loc[j] >= K) { bb2 = tid * 8 + j; break; }
            cum += loc[j];
          }
          sel[0] = (uint32_t)bb2; sel[1] = cum; sel[2] = K - cum;
        }
      }
      __syncthreads();
    }
  }
}

// ---- k_emit: labels/wts (4 anchors/thread); wave-aggregated cand push -----
__global__ __launch_bounds__(256) void k_emit(float* __restrict__ out_lab,
                                              float* __restrict__ out_wts,
                                              uint32_t* __restrict__ ws) {
  int tid = threadIdx.x;
  int t4 = (blockIdx.x * 256 + tid) * 4;     // 4 consecutive hw, same a
  int a = t4 >> 16, hw0 = t4 & 65535;
  uint4 lm4 = *(const uint4*)&ws[OFF_LABM + t4];
  uint32_t bf = ws[OFF_SEL + 0], bbs = ws[OFF_SEL + 4];
  uint32_t Kf = ws[OFF_SEL + 3], Kb = ws[OFF_SEL + 7];
  float inv = 1.0f / (float)(Kf + Kb);       // 1/num_ni
  uint64_t* candf = (uint64_t*)(ws + OFF_CANDF);
  uint64_t* candb = (uint64_t*)(ws + OFF_CANDB);
  uint32_t lane = (uint32_t)(tid & 63);
  unsigned long long below = (1ull << lane) - 1ull;

  float lv[4], wv[4];
  uint32_t lms[4] = {lm4.x, lm4.y, lm4.z, lm4.w};
  #pragma unroll
  for (int j = 0; j < 4; j++) {
    uint32_t lab = lms[j] >> 24;
    uint32_t m = lms[j] & 0x7FFFFFu;
    uint32_t bn = m >> BIN_SHIFT;
    float outv = 2.0f, wvv = 0.0f;
    bool pushf = false, pushb = false;
    if (lab == LAB_FG) {
      if (bn < bf) { outv = 1.0f; wvv = inv; }
      else if (bn == bf) pushf = true;
    } else if (lab == LAB_BG) {
      if (bn < bbs) { outv = 0.0f; }
      else if (bn == bbs) pushb = true;
    }
    // wave-aggregated pushes: one atomic per wave per class
    unsigned long long mkf = __ballot(pushf);
    if (mkf) {
      uint32_t c = (uint32_t)__popcll(mkf);
      int leader = __ffsll(mkf) - 1;
      uint32_t base = 0;
      if ((int)lane == leader) base = atomicAdd(&ws[OFF_CNTF], c);
      base = (uint32_t)__shfl((int)base, leader, 64);
      if (pushf) {
        uint32_t idx = base + (uint32_t)__popcll(mkf & below);
        if (idx < CAND_CAP) {
          uint32_t n = (uint32_t)((hw0 + j) * 9 + a);
          candf[idx] = ((uint64_t)m << 20) | (uint64_t)n;
        }
      }
    }
    unsigned long long mkb = __ballot(pushb);
    if (mkb) {
      uint32_t c = (uint32_t)__popcll(mkb);
      int leader = __ffsll(mkb) - 1;
      uint32_t base = 0;
      if ((int)lane == leader) base = atomicAdd(&ws[OFF_CNTB], c);
      base = (uint32_t)__shfl((int)base, leader, 64);
      if (pushb) {
        uint32_t idx = base + (uint32_t)__popcll(mkb & below);
        if (idx < CAND_CAP) {
          uint32_t n = (uint32_t)((hw0 + j) * 9 + a);
          candb[idx] = ((uint64_t)m << 20) | (uint64_t)n;
        }
      }
    }
    lv[j] = outv; wv[j] = wvv;
  }
  *(float4*)&out_lab[t4] = make_float4(lv[0], lv[1], lv[2], lv[3]);
  float4 wq = make_float4(wv[0], wv[1], wv[2], wv[3]);
  int c4 = a * 4;
  *(float4*)&out_wts[(c4 + 0) * HW + hw0] = wq;
  *(float4*)&out_wts[(c4 + 1) * HW + hw0] = wq;
  *(float4*)&out_wts[(c4 + 2) * HW + hw0] = wq;
  *(float4*)&out_wts[(c4 + 3) * HW + hw0] = wq;
}

// ---- k_fixup: rank boundary candidates (LDS-staged); promote rank < need --
__global__ __launch_bounds__(256) void k_fixup(float* __restrict__ out_lab,
                                               float* __restrict__ out_wts,
                                               uint32_t* __restrict__ ws) {
  __shared__ uint64_t sc[CAND_CAP];          // 32 KB
  int cls = blockIdx.x;
  uint32_t cnt = ws[cls == 0 ? OFF_CNTF : OFF_CNTB];
  uint32_t C = cnt < CAND_CAP ? cnt : CAND_CAP;
  uint32_t need = ws[OFF_SEL + cls * 4 + 2];
  uint32_t Kf = ws[OFF_SEL + 3], Kb = ws[OFF_SEL + 7];
  float inv = 1.0f / (float)(Kf + Kb);
  const uint64_t* cand =
      (const uint64_t*)(ws + (cls == 0 ? OFF_CANDF : OFF_CANDB));
  for (uint32_t i = threadIdx.x; i < C; i += 256) sc[i] = cand[i];
  __syncthreads();
  for (uint32_t i = threadIdx.x; i < C; i += 256) {
    uint64_t k = sc[i];
    uint32_t r = 0;
    for (uint32_t j = 0; j < C; j++) r += (sc[j] < k) ? 1u : 0u;
    if (r < need) {                      // keys unique -> exactly `need` kept
      uint32_t n = (uint32_t)(k & 0xFFFFFu);
      uint32_t aa = n % 9u, hw = n / 9u;
      uint32_t t = aa * HW + hw;
      if (cls == 0) {
        out_lab[t] = 1.0f;
        #pragma unroll
        for (int j = 0; j < 4; j++) out_wts[(aa * 4 + j) * HW + hw] = inv;
      } else {
        out_lab[t] = 0.0f;
      }
    }
  }
}

extern "C" void kernel_launch(void* const* d_in, const int* in_sizes, int n_in,
                              void* d_out, int out_size, void* d_ws,
                              size_t ws_size, hipStream_t stream) {
  const float* gt  = (const float*)d_in[1];
  const int*   imw = (const int*)d_in[2];
  const int*   imh = (const int*)d_in[3];
  float* out      = (float*)d_out;
  float* out_lab  = out;                   // 589824
  float* out_adj  = out + N_ANCH;          // 4*589824
  float* out_wts  = out + 5 * N_ANCH;      // 4*589824
  uint32_t* ws = (uint32_t*)d_ws;          // ~2.44 MB used

  uint32_t kf0, kf1, kb0, kb1;
  tf2x32(0u, 42u, 0u, 0u, &kf0, &kf1);
  tf2x32(0u, 42u, 0u, 1u, &kb0, &kb1);

  hipLaunchKernelGGL(k_pre, dim3(NG * 8), dim3(256), 0, stream, gt, imw, imh,
                     ws);
  hipLaunchKernelGGL(k_main, dim3(NBLK_MAIN), dim3(256), 0, stream, gt, imw,
                     imh, out_adj, ws, kf0, kf1, kb0, kb1);
  hipLaunchKernelGGL(k_emit, dim3(NBLK_EMIT), dim3(256), 0, stream, out_lab,
                     out_wts, ws);
  hipLaunchKernelGGL(k_fixup, dim3(2), dim3(256), 0, stream, out_lab, out_wts,
                     ws);
}